// Round 10
// baseline (3562.453 us; speedup 1.0000x reference)
//
#include <hip/hip_runtime.h>
#include <hip/hip_bf16.h>

// Problem constants (B=8, N=4096, M=N/4, K=64, C_in=64, h=128)
#define BB   8
#define NN   4096
#define MM   1024
#define KK   64
#define CIN  64
#define HH   128

// f32 radius^2 predicate: reference compares f32 d2 against 0.2*0.2.
// The f32 set passing it == all f32 <= 0x3D23D70A = 0.039999999105930328.
#define R2F 0.039999999105930328f

// --------------------------------------------------------------------------
// RESOLVED (R0-R9 forensics): inputs are FLOAT32 in dict order (R9's content
// classifier selected dict); OUTPUT IS FLOAT32 (reference returns f32; R5-R9's
// "impossible" 2.1066 error on centroid copies + chunk1 error == all-zeros
// 454.0 are exactly the signature of bf16 writes packed two-per-f32-slot,
// covering only half the real buffer). The np reference is bf16-ROUNDED
// (R0's exact 1.000000e+00), so we bf16-round every result before storing f32
// -> bit-exact match when discrete selections agree.
// --------------------------------------------------------------------------
static __device__ __forceinline__ float rnd_bf16(float v) {
    return __bfloat162float(__float2bfloat16(v));
}

// ---------------------------------------------------------------------------
// Kernel 1: farthest point sampling. One block per batch, 1024 threads.
// Exact-f32 mind update (RN, no fma -- matches np (dx*dx+dy*dy)+dz*dz), wave
// shuffle-argmax, 16 wave partials in LDS, two barriers/step. Tie-break:
// smallest index (np argmax first-occurrence). Writes f32 centroids to ws
// (exact, for ball query) and bf16-rounded f32 centroids to d_out.
// reshape(B,3,M) is a flat view -> flat order is cent[b][m][xyz].
// ---------------------------------------------------------------------------
__global__ __launch_bounds__(1024) void fps_kernel(
    const float* __restrict__ pts,            // [B,3,N] f32
    float* __restrict__ centf,                // ws [B,M,3] f32 (exact)
    float* __restrict__ outc)                 // d_out (first B*M*3), f32
{
    const int b = blockIdx.x;
    const int t = threadIdx.x;
    __shared__ float lx[NN], ly[NN], lz[NN];
    __shared__ float pv[16];
    __shared__ int   pi[16];

    const float* px = pts + (size_t)b * 3 * NN;
    float x[4], y[4], z[4], mind[4];
#pragma unroll
    for (int i = 0; i < 4; ++i) {
        int p = t + i * 1024;
        x[i] = px[p];
        y[i] = px[NN + p];
        z[i] = px[2 * NN + p];
        lx[p] = x[i]; ly[p] = y[i]; lz[p] = z[i];
        mind[i] = 3.4e38f;
    }
    __syncthreads();

    const int lane = t & 63, wv = t >> 6;
    float bx = lx[0], by = ly[0], bz = lz[0];

    for (int j = 0; j < MM; ++j) {
        if (t == 0) {
            int o = (b * MM + j) * 3;
            centf[o]    = bx; centf[o + 1] = by; centf[o + 2] = bz;
            outc[o]     = rnd_bf16(bx);
            outc[o + 1] = rnd_bf16(by);
            outc[o + 2] = rnd_bf16(bz);
        }
        float v = -1.0f; int bi = 0;
#pragma unroll
        for (int i = 0; i < 4; ++i) {
            float dx = x[i] - bx, dy = y[i] - by, dz = z[i] - bz;
            float d = __fadd_rn(__fadd_rn(__fmul_rn(dx, dx), __fmul_rn(dy, dy)),
                                __fmul_rn(dz, dz));
            float md = fminf(mind[i], d);
            mind[i] = md;
            if (md > v) { v = md; bi = t + i * 1024; }  // strict >: keep smaller idx
        }
#pragma unroll
        for (int off = 32; off >= 1; off >>= 1) {
            float ov = __shfl_xor(v, off);
            int   oi = __shfl_xor(bi, off);
            if (ov > v || (ov == v && oi < bi)) { v = ov; bi = oi; }
        }
        if (lane == 0) { pv[wv] = v; pi[wv] = bi; }
        __syncthreads();
        float bestv = pv[0]; int best = pi[0];
#pragma unroll
        for (int w = 1; w < 16; ++w) {
            float wvv = pv[w]; int wi = pi[w];
            if (wvv > bestv || (wvv == bestv && wi < best)) { bestv = wvv; best = wi; }
        }
        bx = lx[best]; by = ly[best]; bz = lz[best];
        __syncthreads();
    }
}

// ---------------------------------------------------------------------------
// Kernel 2: fused ball-query + point MLP + feature MLP + group max.
// One wave per group, grid = B*M. Structure proven in R6 (ran deterministically
// to completion); only the output dtype changes (f32, bf16-rounded values).
// LDS: 16KB w_s (reused pw2->fw1->fw2) + 17.4KB h2s (reused) + sels ~= 34KB.
// ---------------------------------------------------------------------------
#define H2S 68
__global__ __launch_bounds__(64) void groupnet_kernel(
    const float* __restrict__ pts,             // [B,3,N] f32
    const float* __restrict__ feat,            // [B,CIN,N] f32
    const float* __restrict__ centf,           // ws [B,M,3] f32
    const float* __restrict__ pw1, const float* __restrict__ pb1,
    const float* __restrict__ pw2, const float* __restrict__ pb2,
    const float* __restrict__ pw3, const float* __restrict__ pb3,
    const float* __restrict__ fw1, const float* __restrict__ fb1,
    const float* __restrict__ fw2, const float* __restrict__ fb2,
    const float* __restrict__ fw3, const float* __restrict__ fb3,
    float* __restrict__ outf)                  // d_out + B*M*3: [B,256,M] f32
{
    __shared__ float w_s[CIN * CIN];           // reused: pw2 -> fw1 -> fw2
    __shared__ float h2s[KK * H2S];            // reused: point h2 -> feat h2
    __shared__ int   sels[KK];

    const int g = blockIdx.x;                  // b*M + m
    const int b = g >> 10, m = g & (MM - 1);
    const int lane = threadIdx.x;

    const float* pts_b  = pts  + (size_t)b * 3 * NN;
    const float* feat_b = feat + (size_t)b * CIN * NN;
    const float cx = centf[(size_t)g * 3];
    const float cy = centf[(size_t)g * 3 + 1];
    const float cz = centf[(size_t)g * 3 + 2];

    for (int i = lane; i < CIN * CIN; i += 64) w_s[i] = pw2[i];

    // ---- 1) ball query (wave-cooperative, exact f32 predicate) ----
    int cnt = 0, first = 0;
    bool have_first = false;
    for (int base = 0; base < NN; base += 64) {
        int p = base + lane;
        float dx = pts_b[p]          - cx;
        float dy = pts_b[NN + p]     - cy;
        float dz = pts_b[2 * NN + p] - cz;
        float d2 = __fadd_rn(__fadd_rn(__fmul_rn(dx, dx), __fmul_rn(dy, dy)),
                             __fmul_rn(dz, dz));
        bool in = (d2 <= R2F);
        unsigned long long mask = __ballot(in);
        if (!have_first && mask != 0ULL) {
            first = base + (int)__builtin_ctzll(mask);
            have_first = true;
        }
        int pos = cnt + (int)__popcll(mask & ((1ULL << lane) - 1ULL));
        if (in && pos < KK) sels[pos] = p;
        cnt += (int)__popcll(mask);
        if (cnt >= KK) break;                  // cnt is wave-uniform
    }
    if (cnt < KK) {
        // centroid is itself a point (d2 == 0) -> have_first always true
        for (int q = cnt + lane; q < KK; q += 64) sels[q] = first;
    }
    __syncthreads();                           // sels + w_s(pw2) visible

    const int s = sels[lane];
    float* ob = outf + (size_t)b * 256 * MM + m;

    // ---- 2) point path: layers 1-2 (lane = group slot k) ----
    {
        const float x = pts_b[s]          - cx;
        const float y = pts_b[NN + s]     - cy;
        const float z = pts_b[2 * NN + s] - cz;
        float h1[CIN];
#pragma unroll
        for (int o = 0; o < CIN; ++o) {
            float acc = pb1[o];
            acc = fmaf(x, pw1[o * 3 + 0], acc);
            acc = fmaf(y, pw1[o * 3 + 1], acc);
            acc = fmaf(z, pw1[o * 3 + 2], acc);
            h1[o] = fmaxf(acc, 0.f);
        }
        for (int o4 = 0; o4 < CIN / 4; ++o4) {
            float4 hv; float* hp = &hv.x;
#pragma unroll
            for (int q = 0; q < 4; ++q) {
                int o = o4 * 4 + q;
                float acc = pb2[o];
#pragma unroll
                for (int c = 0; c < CIN; ++c) acc = fmaf(h1[c], w_s[o * CIN + c], acc);
                hp[q] = fmaxf(acc, 0.f);
            }
            *(float4*)&h2s[lane * H2S + o4 * 4] = hv;
        }
    }
    __syncthreads();

    // ---- point layer 3 + group max -> out ch 128..255 ----
    {
        float w3a[CIN], w3b[CIN];
#pragma unroll
        for (int c = 0; c < CIN; ++c) {
            w3a[c] = pw3[(size_t)lane * CIN + c];
            w3b[c] = pw3[(size_t)(lane + 64) * CIN + c];
        }
        const float b3a = pb3[lane], b3b = pb3[lane + 64];
        float pa = -3.4e38f, pbv = -3.4e38f;
        for (int k = 0; k < KK; ++k) {
            float va = b3a, vb = b3b;
#pragma unroll
            for (int c4 = 0; c4 < CIN / 4; ++c4) {
                float4 h = *(const float4*)&h2s[k * H2S + c4 * 4];
                va = fmaf(h.x, w3a[c4 * 4 + 0], va); vb = fmaf(h.x, w3b[c4 * 4 + 0], vb);
                va = fmaf(h.y, w3a[c4 * 4 + 1], va); vb = fmaf(h.y, w3b[c4 * 4 + 1], vb);
                va = fmaf(h.z, w3a[c4 * 4 + 2], va); vb = fmaf(h.z, w3b[c4 * 4 + 2], vb);
                va = fmaf(h.w, w3a[c4 * 4 + 3], va); vb = fmaf(h.w, w3b[c4 * 4 + 3], vb);
            }
            pa = fmaxf(pa, va); pbv = fmaxf(pbv, vb);
        }
        ob[(size_t)(128 + lane) * MM] = rnd_bf16(pa);
        ob[(size_t)(192 + lane) * MM] = rnd_bf16(pbv);
    }
    __syncthreads();                           // h2s + w_s reads done

    // ---- 3) feature path: reload weights, recompute per point ----
    for (int i = lane; i < CIN * CIN; i += 64) w_s[i] = fw1[i];
    __syncthreads();                           // w_s = fw1

    float h1f[CIN];
    {
        float f[CIN];
#pragma unroll
        for (int c = 0; c < CIN; ++c) f[c] = feat_b[(size_t)c * NN + s];
        for (int o = 0; o < CIN; ++o) {
            float acc = fb1[o];
#pragma unroll
            for (int c = 0; c < CIN; ++c) acc = fmaf(f[c], w_s[o * CIN + c], acc);
            h1f[o] = fmaxf(acc, 0.f);
        }
    }
    __syncthreads();                           // w_s(fw1) reads done
    for (int i = lane; i < CIN * CIN; i += 64) w_s[i] = fw2[i];
    __syncthreads();                           // w_s = fw2

    for (int o4 = 0; o4 < CIN / 4; ++o4) {
        float4 hv; float* hp = &hv.x;
#pragma unroll
        for (int q = 0; q < 4; ++q) {
            int o = o4 * 4 + q;
            float acc = fb2[o];
#pragma unroll
            for (int c = 0; c < CIN; ++c) acc = fmaf(h1f[c], w_s[o * CIN + c], acc);
            hp[q] = fmaxf(acc, 0.f);
        }
        *(float4*)&h2s[lane * H2S + o4 * 4] = hv;
    }
    __syncthreads();

    // ---- feature layer 3 + group max -> out ch 0..127 ----
    {
        float w3a[CIN], w3b[CIN];
#pragma unroll
        for (int c = 0; c < CIN; ++c) {
            w3a[c] = fw3[(size_t)lane * CIN + c];
            w3b[c] = fw3[(size_t)(lane + 64) * CIN + c];
        }
        const float b3a = fb3[lane], b3b = fb3[lane + 64];
        float fa = -3.4e38f, fbv = -3.4e38f;
        for (int k = 0; k < KK; ++k) {
            float va = b3a, vb = b3b;
#pragma unroll
            for (int c4 = 0; c4 < CIN / 4; ++c4) {
                float4 h = *(const float4*)&h2s[k * H2S + c4 * 4];
                va = fmaf(h.x, w3a[c4 * 4 + 0], va); vb = fmaf(h.x, w3b[c4 * 4 + 0], vb);
                va = fmaf(h.y, w3a[c4 * 4 + 1], va); vb = fmaf(h.y, w3b[c4 * 4 + 1], vb);
                va = fmaf(h.z, w3a[c4 * 4 + 2], va); vb = fmaf(h.z, w3b[c4 * 4 + 2], vb);
                va = fmaf(h.w, w3a[c4 * 4 + 3], va); vb = fmaf(h.w, w3b[c4 * 4 + 3], vb);
            }
            fa = fmaxf(fa, va); fbv = fmaxf(fbv, vb);
        }
        ob[(size_t)lane * MM]        = rnd_bf16(fa);
        ob[(size_t)(lane + 64) * MM] = rnd_bf16(fbv);
    }
}

extern "C" void kernel_launch(void* const* d_in, const int* in_sizes, int n_in,
                              void* d_out, int out_size, void* d_ws, size_t ws_size,
                              hipStream_t stream) {
    // Inputs: float32, setup_inputs dict order (confirmed by R9's on-device
    // content classifier selecting the identity mapping).
    const float* pts  = (const float*)d_in[0];
    const float* feat = (const float*)d_in[1];
    const float* pw1  = (const float*)d_in[2];
    const float* pb1  = (const float*)d_in[3];
    const float* pw2  = (const float*)d_in[4];
    const float* pb2  = (const float*)d_in[5];
    const float* pw3  = (const float*)d_in[6];
    const float* pb3  = (const float*)d_in[7];
    const float* fw1  = (const float*)d_in[8];
    const float* fb1  = (const float*)d_in[9];
    const float* fw2  = (const float*)d_in[10];
    const float* fb2  = (const float*)d_in[11];
    const float* fw3  = (const float*)d_in[12];
    const float* fb3  = (const float*)d_in[13];

    float* out = (float*)d_out;                // OUTPUT IS FLOAT32

    // ws: 96KB f32 centroids only.
    float* centf = (float*)d_ws;

    fps_kernel<<<BB, 1024, 0, stream>>>(pts, centf, out);
    groupnet_kernel<<<BB * MM, 64, 0, stream>>>(
        pts, feat, centf,
        pw1, pb1, pw2, pb2, pw3, pb3,
        fw1, fb1, fw2, fb2, fw3, fb3,
        out + (size_t)BB * MM * 3);
}

// Round 11
// 1133.221 us; speedup vs baseline: 3.1437x; 3.1437x over previous
//
#include <hip/hip_runtime.h>
#include <hip/hip_bf16.h>

// Problem constants (B=8, N=4096, M=N/4, K=64, C_in=64, h=128)
#define BB   8
#define NN   4096
#define MM   1024
#define KK   64
#define CIN  64
#define HH   128

// f32 radius^2 predicate: largest f32 <= 0.2*0.2 (f64) = 0x3D23D70A.
#define R2F 0.039999999105930328f

// Inputs: f32, dict order. Output: f32, values bf16-rounded (matches np ref;
// R10 passed with absmax 0.0).
static __device__ __forceinline__ float rnd_bf16(float v) {
    return __bfloat162float(__float2bfloat16(v));
}

// ---------------------------------------------------------------------------
// Kernel 1: FPS, latency-optimized. One block/batch, 256 threads (4 waves),
// 16 points per thread IN REGISTERS. Per step:
//   - update mind[16] (exact RN f32, np order) + thread-local argmax
//     (strict > keeps smallest index within the thread's strided set)
//   - pack key = (bits(bestd)<<32) | (0xFFFFFFFF - idx): u64 max == largest
//     dist, ties -> smallest idx (np argmax first-occurrence). Valid because
//     dists are nonneg finite (IEEE bits monotone).
//   - one LDS atomicMax per thread into a 4-slot rotating key buffer
//     (slot j&3 written at step j; slot (j+2)&3 reset by t0 at step j --
//     separated from its readers (step j-2) by barrier(j-1) and from its
//     writers (step j+2) by barriers j,j+1) -> ONE barrier per step.
// Replaces R10's 6-dependent-shuffle chain (~720cyc) + two 16-wave barriers.
// ---------------------------------------------------------------------------
__global__ __launch_bounds__(256) void fps_kernel(
    const float* __restrict__ pts,            // [B,3,N] f32
    float* __restrict__ centf,                // ws [B,M,3] f32 (exact)
    float* __restrict__ outc)                 // d_out (first B*M*3), f32
{
    const int b = blockIdx.x;
    const int t = threadIdx.x;
    __shared__ float lx[NN], ly[NN], lz[NN];
    __shared__ unsigned long long akey[4];

    const float* px = pts + (size_t)b * 3 * NN;
    float x[16], y[16], z[16], mind[16];
#pragma unroll
    for (int i = 0; i < 16; ++i) {
        int p = t + i * 256;                  // coalesced
        x[i] = px[p];
        y[i] = px[NN + p];
        z[i] = px[2 * NN + p];
        lx[p] = x[i]; ly[p] = y[i]; lz[p] = z[i];
        mind[i] = 3.4e38f;
    }
    if (t < 4) akey[t] = 0ULL;
    __syncthreads();

    float bx = lx[0], by = ly[0], bz = lz[0];

    for (int j = 0; j < MM; ++j) {
        if (t == 0) {
            int o = (b * MM + j) * 3;
            centf[o]    = bx; centf[o + 1] = by; centf[o + 2] = bz;
            outc[o]     = rnd_bf16(bx);
            outc[o + 1] = rnd_bf16(by);
            outc[o + 2] = rnd_bf16(bz);
            akey[(j + 2) & 3] = 0ULL;         // reset future slot (race-free)
        }
        float bd = -1.0f; int bi = 0;
#pragma unroll
        for (int i = 0; i < 16; ++i) {
            float dx = x[i] - bx, dy = y[i] - by, dz = z[i] - bz;
            // exact np order: (dx*dx + dy*dy) + dz*dz, RN, no fma
            float d = __fadd_rn(__fadd_rn(__fmul_rn(dx, dx), __fmul_rn(dy, dy)),
                                __fmul_rn(dz, dz));
            float md = fminf(mind[i], d);
            mind[i] = md;
            if (md > bd) { bd = md; bi = t + i * 256; }  // strict >: smaller idx
        }
        unsigned long long key =
            ((unsigned long long)__float_as_uint(bd) << 32) |
            (unsigned long long)(0xFFFFFFFFu - (unsigned)bi);
        atomicMax(&akey[j & 3], key);
        __syncthreads();
        unsigned long long bk = akey[j & 3];
        int best = (int)(0xFFFFFFFFu - (unsigned)(bk & 0xFFFFFFFFULL));
        bx = lx[best]; by = ly[best]; bz = lz[best];
    }
}

// ---------------------------------------------------------------------------
// Kernel 2: per-point feature MLP cache (1x1 convs depend only on the point
// -> compute once per point, 16x fewer FLOPs than per-group recompute).
// One thread per point; w1,w2 staged f32 in LDS; w3/biases lane-uniform from
// global (scalarized). Output bf16 [B,N,HH] to ws -- EXACT under the group
// max (RNE monotone => round-then-max == max-then-round).
// ---------------------------------------------------------------------------
__global__ __launch_bounds__(256) void featmlp_kernel(
    const float* __restrict__ feat,            // [B,CIN,N] f32
    const float* __restrict__ fw1, const float* __restrict__ fb1,
    const float* __restrict__ fw2, const float* __restrict__ fb2,
    const float* __restrict__ fw3, const float* __restrict__ fb3,
    __hip_bfloat16* __restrict__ out)          // ws [B,N,HH] bf16
{
    __shared__ float w1[CIN * CIN], w2[CIN * CIN];
    const int tid = threadIdx.x;
    for (int i = tid; i < CIN * CIN; i += 256) { w1[i] = fw1[i]; w2[i] = fw2[i]; }
    __syncthreads();

    const int gid = blockIdx.x * 256 + tid;    // b*N + n
    const int b = gid >> 12, n = gid & (NN - 1);
    const float* fp = feat + (size_t)b * CIN * NN + n;

    float f[CIN];
#pragma unroll
    for (int c = 0; c < CIN; ++c) f[c] = fp[(size_t)c * NN];

    float h1[CIN];
    for (int o = 0; o < CIN; ++o) {
        float acc = fb1[o];
#pragma unroll
        for (int c = 0; c < CIN; ++c) acc = fmaf(f[c], w1[o * CIN + c], acc);
        h1[o] = fmaxf(acc, 0.f);
    }
    float h2[CIN];
    for (int o = 0; o < CIN; ++o) {
        float acc = fb2[o];
#pragma unroll
        for (int c = 0; c < CIN; ++c) acc = fmaf(h1[c], w2[o * CIN + c], acc);
        h2[o] = fmaxf(acc, 0.f);
    }
    __hip_bfloat16* op = out + (size_t)gid * HH;
    for (int o = 0; o < HH; ++o) {
        float acc = fb3[o];
#pragma unroll
        for (int c = 0; c < CIN; ++c) acc = fmaf(h2[c], fw3[o * CIN + c], acc);
        op[o] = __float2bfloat16(acc);
    }
}

// ---------------------------------------------------------------------------
// Kernel 3: fused ball-query + point MLP + max + feature gather-max.
// One wave per group, grid = B*M. vs R10: feature path is now a gather-max of
// the bf16 cache (removes 2/3 of FLOPs + two weight reloads/barriers), and
// pw2 is read lane-uniform from global (K$/s_load) instead of LDS staging
// -> LDS 34KB -> ~18KB -> ~8 blocks/CU occupancy.
// ---------------------------------------------------------------------------
#define H2S 68
__global__ __launch_bounds__(64) void groupnet_kernel(
    const float* __restrict__ pts,             // [B,3,N] f32
    const float* __restrict__ centf,           // ws [B,M,3] f32
    const __hip_bfloat16* __restrict__ fout,   // ws [B,N,HH] bf16
    const float* __restrict__ pw1, const float* __restrict__ pb1,
    const float* __restrict__ pw2, const float* __restrict__ pb2,
    const float* __restrict__ pw3, const float* __restrict__ pb3,
    float* __restrict__ outf)                  // d_out + B*M*3: [B,256,M] f32
{
    __shared__ float h2s[KK * H2S];
    __shared__ int   sels[KK];

    const int g = blockIdx.x;                  // b*M + m
    const int b = g >> 10, m = g & (MM - 1);
    const int lane = threadIdx.x;

    const float* pts_b = pts + (size_t)b * 3 * NN;
    const float cx = centf[(size_t)g * 3];
    const float cy = centf[(size_t)g * 3 + 1];
    const float cz = centf[(size_t)g * 3 + 2];

    // ---- 1) ball query (wave-cooperative, exact f32 predicate) ----
    int cnt = 0, first = 0;
    bool have_first = false;
    for (int base = 0; base < NN; base += 64) {
        int p = base + lane;
        float dx = pts_b[p]          - cx;
        float dy = pts_b[NN + p]     - cy;
        float dz = pts_b[2 * NN + p] - cz;
        float d2 = __fadd_rn(__fadd_rn(__fmul_rn(dx, dx), __fmul_rn(dy, dy)),
                             __fmul_rn(dz, dz));
        bool in = (d2 <= R2F);
        unsigned long long mask = __ballot(in);
        if (!have_first && mask != 0ULL) {
            first = base + (int)__builtin_ctzll(mask);
            have_first = true;
        }
        int pos = cnt + (int)__popcll(mask & ((1ULL << lane) - 1ULL));
        if (in && pos < KK) sels[pos] = p;
        cnt += (int)__popcll(mask);
        if (cnt >= KK) break;                  // cnt is wave-uniform
    }
    if (cnt < KK) {
        for (int q = cnt + lane; q < KK; q += 64) sels[q] = first;
    }
    __syncthreads();                           // sels visible

    const int s = sels[lane];
    float* ob = outf + (size_t)b * 256 * MM + m;

    // ---- 2) point path layers 1-2 (lane = group slot k); pw2 via K$ ----
    {
        const float x = pts_b[s]          - cx;
        const float y = pts_b[NN + s]     - cy;
        const float z = pts_b[2 * NN + s] - cz;
        float h1[CIN];
#pragma unroll
        for (int o = 0; o < CIN; ++o) {
            float acc = pb1[o];
            acc = fmaf(x, pw1[o * 3 + 0], acc);
            acc = fmaf(y, pw1[o * 3 + 1], acc);
            acc = fmaf(z, pw1[o * 3 + 2], acc);
            h1[o] = fmaxf(acc, 0.f);
        }
        for (int o4 = 0; o4 < CIN / 4; ++o4) {
            float4 hv; float* hp = &hv.x;
#pragma unroll
            for (int q = 0; q < 4; ++q) {
                int o = o4 * 4 + q;
                float acc = pb2[o];
#pragma unroll
                for (int c = 0; c < CIN; ++c) acc = fmaf(h1[c], pw2[o * CIN + c], acc);
                hp[q] = fmaxf(acc, 0.f);
            }
            *(float4*)&h2s[lane * H2S + o4 * 4] = hv;
        }
    }
    __syncthreads();

    // ---- 3) point layer 3 + group max -> out ch 128..255 ----
    {
        float w3a[CIN], w3b[CIN];
#pragma unroll
        for (int c = 0; c < CIN; ++c) {
            w3a[c] = pw3[(size_t)lane * CIN + c];
            w3b[c] = pw3[(size_t)(lane + 64) * CIN + c];
        }
        const float b3a = pb3[lane], b3b = pb3[lane + 64];
        float pa = -3.4e38f, pbv = -3.4e38f;
        for (int k = 0; k < KK; ++k) {
            float va = b3a, vb = b3b;
#pragma unroll
            for (int c4 = 0; c4 < CIN / 4; ++c4) {
                float4 h = *(const float4*)&h2s[k * H2S + c4 * 4];
                va = fmaf(h.x, w3a[c4 * 4 + 0], va); vb = fmaf(h.x, w3b[c4 * 4 + 0], vb);
                va = fmaf(h.y, w3a[c4 * 4 + 1], va); vb = fmaf(h.y, w3b[c4 * 4 + 1], vb);
                va = fmaf(h.z, w3a[c4 * 4 + 2], va); vb = fmaf(h.z, w3b[c4 * 4 + 2], vb);
                va = fmaf(h.w, w3a[c4 * 4 + 3], va); vb = fmaf(h.w, w3b[c4 * 4 + 3], vb);
            }
            pa = fmaxf(pa, va); pbv = fmaxf(pbv, vb);
        }
        ob[(size_t)(128 + lane) * MM] = rnd_bf16(pa);
        ob[(size_t)(192 + lane) * MM] = rnd_bf16(pbv);
    }

    // ---- 4) feature gather-max (bf16 cache) -> out ch 0..127 ----
    {
        const __hip_bfloat16* fb_ = fout + (size_t)b * NN * HH;
        float fa = -3.4e38f, fbv = -3.4e38f;
        for (int k = 0; k < KK; ++k) {
            const __hip_bfloat16* fp = fb_ + (size_t)sels[k] * HH;
            fa  = fmaxf(fa,  __bfloat162float(fp[lane]));
            fbv = fmaxf(fbv, __bfloat162float(fp[lane + 64]));
        }
        ob[(size_t)lane * MM]        = fa;     // already bf16-exact values
        ob[(size_t)(lane + 64) * MM] = fbv;
    }
}

extern "C" void kernel_launch(void* const* d_in, const int* in_sizes, int n_in,
                              void* d_out, int out_size, void* d_ws, size_t ws_size,
                              hipStream_t stream) {
    const float* pts  = (const float*)d_in[0];
    const float* feat = (const float*)d_in[1];
    const float* pw1  = (const float*)d_in[2];
    const float* pb1  = (const float*)d_in[3];
    const float* pw2  = (const float*)d_in[4];
    const float* pb2  = (const float*)d_in[5];
    const float* pw3  = (const float*)d_in[6];
    const float* pb3  = (const float*)d_in[7];
    const float* fw1  = (const float*)d_in[8];
    const float* fb1  = (const float*)d_in[9];
    const float* fw2  = (const float*)d_in[10];
    const float* fb2  = (const float*)d_in[11];
    const float* fw3  = (const float*)d_in[12];
    const float* fb3  = (const float*)d_in[13];

    float* out = (float*)d_out;                // f32 output

    // ws: [0, 96KB) f32 centroids; [96KB, +8.39MB) bf16 feature-MLP cache.
    // (R1 wrote 18.9MB of ws without fault -> ws_size covers 8.5MB.)
    float* centf = (float*)d_ws;
    __hip_bfloat16* fout = (__hip_bfloat16*)((char*)d_ws + (size_t)BB * MM * 3 * 4);

    featmlp_kernel<<<(BB * NN) / 256, 256, 0, stream>>>(
        feat, fw1, fb1, fw2, fb2, fw3, fb3, fout);
    fps_kernel<<<BB, 256, 0, stream>>>(pts, centf, out);
    groupnet_kernel<<<BB * MM, 64, 0, stream>>>(
        pts, centf, fout,
        pw1, pb1, pw2, pb2, pw3, pb3,
        out + (size_t)BB * MM * 3);
}